// Round 2
// baseline (3254.372 us; speedup 1.0000x reference)
//
#include <hip/hip_runtime.h>

typedef unsigned short u16;
typedef unsigned int   u32;
typedef __bf16  bf16x8 __attribute__((ext_vector_type(8)));
typedef float   f32x4  __attribute__((ext_vector_type(4)));

#define B_ 8192
#define DI __device__ __forceinline__

DI u16 f2bf(float f) {
  u32 u = __float_as_uint(f);
  u = (u + 0x7fffu + ((u >> 16) & 1u)) >> 16;   // RNE
  return (u16)u;
}
DI float bf2f(u16 h) { return __uint_as_float(((u32)h) << 16); }

// ---------------- weight transpose + cast: W[g][K][N] f32 -> Wt[g][N][K] bf16
__global__ __launch_bounds__(256) void transpose_cast(
    const float* __restrict__ W, u16* __restrict__ Wt, int K, int N) {
  __shared__ float tile[64][65];
  int g = blockIdx.z;
  int k0 = blockIdx.x * 64, n0 = blockIdx.y * 64;
  const float* Wg = W + (size_t)g * K * N;
  u16* Og = Wt + (size_t)g * N * K;
  int tid = threadIdx.x;
  int rr = tid >> 4, cc = (tid & 15) * 4;
#pragma unroll
  for (int r = 0; r < 4; ++r) {
    int k = rr + r * 16;
    float4 v = *(const float4*)(Wg + (size_t)(k0 + k) * N + n0 + cc);
    tile[k][cc] = v.x; tile[k][cc + 1] = v.y; tile[k][cc + 2] = v.z; tile[k][cc + 3] = v.w;
  }
  __syncthreads();
  int nr = tid >> 3, kc = (tid & 7) * 8;
#pragma unroll
  for (int p = 0; p < 2; ++p) {
    int n = nr + p * 32;
    u16 tmp[8];
#pragma unroll
    for (int j = 0; j < 8; ++j) tmp[j] = f2bf(tile[kc + j][n]);
    *(uint4*)(Og + (size_t)(n0 + n) * K + k0 + kc) = *(uint4*)tmp;
  }
}

// ---------------- f32 -> bf16 cast (4 elems/thread)
__global__ __launch_bounds__(256) void cast_bf16k(const float* __restrict__ X, u16* __restrict__ Y) {
  size_t i = ((size_t)blockIdx.x * 256 + threadIdx.x) * 4;
  float4 v = *(const float4*)(X + i);
  u16 t[4] = { f2bf(v.x), f2bf(v.y), f2bf(v.z), f2bf(v.w) };
  *(uint2*)(Y + i) = *(uint2*)t;
}

// ---------------- batched bf16 GEMM (z-local output slots, global A select)
// A row-select: (a_g0 + z)/a_div picks the A matrix (stride a_stride elems)
// Wt: [z][N][K] bf16 (pre-offset); bias: [z][N] (pre-offset); C: [z][B_][N] (pre-offset)
#define BM 128
#define BN 128
#define BK 32
#define LDA 40   // padded LDS row stride in u16 (80B)

__global__ __launch_bounds__(256) void gemm_bf16(
    const u16* __restrict__ A, long a_stride, int a_div, int a_g0,
    const u16* __restrict__ Wt, const float* __restrict__ bias,
    u16* __restrict__ C, int N, int K, int relu_flag) {
  int gz = blockIdx.z;
  const u16* Ag = A + (size_t)((a_g0 + gz) / a_div) * a_stride;
  const u16* Wg = Wt + (size_t)gz * N * K;
  u16* Cg = C + (size_t)gz * B_ * N;
  int m0 = blockIdx.x * BM, n0 = blockIdx.y * BN;

  __shared__ __align__(16) u16 As[BM * LDA];
  __shared__ __align__(16) u16 Bs[BN * LDA];

  int tid = threadIdx.x;
  int wave = tid >> 6, lane = tid & 63;
  int wm = (wave >> 1) * 64, wn = (wave & 1) * 64;
  int lr = lane & 15, lk = (lane >> 4) * 8;

  int srow = tid >> 2;        // 0..63
  int scol = (tid & 3) * 8;   // 0,8,16,24

  f32x4 acc[4][4];
#pragma unroll
  for (int i = 0; i < 4; ++i)
#pragma unroll
    for (int j = 0; j < 4; ++j)
      acc[i][j] = (f32x4){0.f, 0.f, 0.f, 0.f};

  const u16* aP0 = Ag + (size_t)(m0 + srow) * K + scol;
  const u16* aP1 = Ag + (size_t)(m0 + 64 + srow) * K + scol;
  const u16* bP0 = Wg + (size_t)(n0 + srow) * K + scol;
  const u16* bP1 = Wg + (size_t)(n0 + 64 + srow) * K + scol;

  int nk = K / BK;
  for (int ks = 0; ks < nk; ++ks) {
    uint4 a0 = *(const uint4*)(aP0 + ks * BK);
    uint4 a1 = *(const uint4*)(aP1 + ks * BK);
    uint4 b0 = *(const uint4*)(bP0 + ks * BK);
    uint4 b1 = *(const uint4*)(bP1 + ks * BK);
    __syncthreads();
    *(uint4*)(As + srow * LDA + scol) = a0;
    *(uint4*)(As + (64 + srow) * LDA + scol) = a1;
    *(uint4*)(Bs + srow * LDA + scol) = b0;
    *(uint4*)(Bs + (64 + srow) * LDA + scol) = b1;
    __syncthreads();
    bf16x8 af[4], bfr[4];
#pragma unroll
    for (int i = 0; i < 4; ++i) {
      union { uint4 u; bf16x8 v; } ua, ub;
      ua.u = *(const uint4*)(As + (wm + i * 16 + lr) * LDA + lk);
      ub.u = *(const uint4*)(Bs + (wn + i * 16 + lr) * LDA + lk);
      af[i] = ua.v; bfr[i] = ub.v;
    }
#pragma unroll
    for (int i = 0; i < 4; ++i)
#pragma unroll
      for (int j = 0; j < 4; ++j)
        acc[i][j] = __builtin_amdgcn_mfma_f32_16x16x32_bf16(af[i], bfr[j], acc[i][j], 0, 0, 0);
  }

  // epilogue: D row = (lane>>4)*4+reg, col = lane&15 (verified gfx950 C/D layout)
  int mr = (lane >> 4) * 4;
#pragma unroll
  for (int i = 0; i < 4; ++i) {
#pragma unroll
    for (int j = 0; j < 4; ++j) {
      int n = n0 + wn + j * 16 + lr;
      float bv = bias[(size_t)gz * N + n];
#pragma unroll
      for (int r = 0; r < 4; ++r) {
        int m = m0 + wm + i * 16 + mr + r;
        float v = acc[i][j][r] + bv;
        if (relu_flag) v = fmaxf(v, 0.f);
        Cg[(size_t)m * N + n] = f2bf(v);
      }
    }
  }
}

// ---------------- rowwise LayerNorm * gain + beta, ReLU, in-place on bf16
// gain/beta pre-offset to the launch's first group; grp = row / B_
__global__ __launch_bounds__(256) void ln_affine_relu(
    u16* __restrict__ H, const float* __restrict__ gain, const float* __restrict__ beta, int N) {
  __shared__ float red[4];
  size_t row = blockIdx.x;
  int grp = (int)(row / B_);
  u16* hp = H + row * N;
  const float* gp = gain + (size_t)grp * N;
  const float* bp = beta + (size_t)grp * N;
  int tid = threadIdx.x;
  int VPT = N >> 8;  // 4 or 8
  float vals[8];
  float s = 0.f;
  for (int i = 0; i < VPT; ++i) { float xv = bf2f(hp[tid + (i << 8)]); vals[i] = xv; s += xv; }
  for (int off = 32; off > 0; off >>= 1) s += __shfl_down(s, off, 64);
  if ((tid & 63) == 0) red[tid >> 6] = s;
  __syncthreads();
  float mu = (red[0] + red[1] + red[2] + red[3]) / (float)N;
  float q = 0.f;
  for (int i = 0; i < VPT; ++i) { float d = vals[i] - mu; q += d * d; }
  __syncthreads();
  for (int off = 32; off > 0; off >>= 1) q += __shfl_down(q, off, 64);
  if ((tid & 63) == 0) red[tid >> 6] = q;
  __syncthreads();
  float var = (red[0] + red[1] + red[2] + red[3]) / (float)N;
  float rstd = rsqrtf(var + 1e-5f);
  for (int i = 0; i < VPT; ++i) {
    int c = tid + (i << 8);
    float y = (vals[i] - mu) * rstd * gp[c] + bp[c];
    hp[c] = f2bf(fmaxf(y, 0.f));
  }
}

// ---------------- fp32 gate logits + softmax: out[t][b][e]
__global__ __launch_bounds__(256) void gate_softmax(
    const void* __restrict__ X, int is_bf16, long t_stride,
    const float* __restrict__ GW, const float* __restrict__ GB,
    float* __restrict__ out, int T_, int K_, int E_, int lpg) {
  __shared__ float logits[32];
  int b = blockIdx.x, tid = threadIdx.x;
  int g = tid / lpg, li = tid % lpg;
  int G = T_ * E_;
  if (g < G) {
    int t = g / E_, e = g % E_;
    const float* gwp = GW + (size_t)t * K_ * E_ + e;
    float s = 0.f;
    if (is_bf16) {
      const u16* xr = (const u16*)X + (size_t)t * t_stride + (size_t)b * K_;
      for (int k = li; k < K_; k += lpg) s += bf2f(xr[k]) * gwp[(size_t)k * E_];
    } else {
      const float* xr = (const float*)X + (size_t)t * t_stride + (size_t)b * K_;
      for (int k = li; k < K_; k += lpg) s += xr[k] * gwp[(size_t)k * E_];
    }
    for (int off = lpg >> 1; off > 0; off >>= 1) s += __shfl_down(s, off, lpg);
    if (li == 0) logits[g] = s + GB[t * E_ + e];
  }
  __syncthreads();
  if (tid < T_) {
    float mx = -1e30f;
    for (int e = 0; e < E_; ++e) mx = fmaxf(mx, logits[tid * E_ + e]);
    float ex[16], sum = 0.f;
    for (int e = 0; e < E_; ++e) { ex[e] = expf(logits[tid * E_ + e] - mx); sum += ex[e]; }
    float inv = 1.f / sum;
    for (int e = 0; e < E_; ++e) out[((size_t)tid * B_ + b) * E_ + e] = ex[e] * inv;
  }
}

// ---------------- MMoE mixing: task_hs[t]=sum_e g[t,e]*eo[e]; shared=mean_t
__global__ __launch_bounds__(256) void mmoe_mix(
    const u16* __restrict__ eo, const float* __restrict__ gates,
    u16* __restrict__ task_hs, u16* __restrict__ shared_h) {
  __shared__ float g[24];
  int b = blockIdx.x, tid = threadIdx.x;
  if (tid < 24) g[tid] = gates[((size_t)(tid >> 3) * B_ + b) * 8 + (tid & 7)];
  __syncthreads();
  int o = tid * 2;
  float a0[3] = {0, 0, 0}, a1[3] = {0, 0, 0};
#pragma unroll
  for (int e = 0; e < 8; ++e) {
    u32 w = *(const u32*)(eo + ((size_t)e * B_ + b) * 512 + o);
    float v0 = bf2f((u16)(w & 0xffffu)), v1 = bf2f((u16)(w >> 16));
#pragma unroll
    for (int t = 0; t < 3; ++t) { a0[t] += g[t * 8 + e] * v0; a1[t] += g[t * 8 + e] * v1; }
  }
  float s0 = 0.f, s1 = 0.f;
#pragma unroll
  for (int t = 0; t < 3; ++t) {
    u16 p[2] = { f2bf(a0[t]), f2bf(a1[t]) };
    *(u32*)(task_hs + ((size_t)t * B_ + b) * 512 + o) = *(u32*)p;
    s0 += a0[t]; s1 += a1[t];
  }
  u16 p[2] = { f2bf(s0 * (1.f / 3.f)), f2bf(s1 * (1.f / 3.f)) };
  *(u32*)(shared_h + (size_t)b * 512 + o) = *(u32*)p;
}

// ---------------- CGC mixing (task experts first, then shared; opt shared-gate out)
__global__ __launch_bounds__(256) void cgc_mix(
    const u16* __restrict__ to, const u16* __restrict__ so,
    const float* __restrict__ g, const float* __restrict__ sg,
    u16* __restrict__ task_out, u16* __restrict__ shared_out) {
  int b = blockIdx.x, o = threadIdx.x;
  float tv[9], sv[4];
#pragma unroll
  for (int j = 0; j < 9; ++j) tv[j] = bf2f(to[((size_t)j * B_ + b) * 256 + o]);
#pragma unroll
  for (int s = 0; s < 4; ++s) sv[s] = bf2f(so[((size_t)s * B_ + b) * 256 + o]);
#pragma unroll
  for (int t = 0; t < 3; ++t) {
    const float* gt = g + ((size_t)t * B_ + b) * 7;
    float a = gt[0] * tv[t * 3] + gt[1] * tv[t * 3 + 1] + gt[2] * tv[t * 3 + 2];
#pragma unroll
    for (int s = 0; s < 4; ++s) a += gt[3 + s] * sv[s];
    task_out[((size_t)t * B_ + b) * 256 + o] = f2bf(a);
  }
  if (shared_out) {
    const float* sp = sg + (size_t)b * 13;
    float a = 0.f;
#pragma unroll
    for (int j = 0; j < 9; ++j) a += sp[j] * tv[j];
#pragma unroll
    for (int s = 0; s < 4; ++s) a += sp[9 + s] * sv[s];
    shared_out[(size_t)b * 256 + o] = f2bf(a);
  }
}

// ---------------- tower head: out[t*B+b] = th[t,b,:] . w2[t,:] + b2[t]  (fp32 out)
__global__ __launch_bounds__(256) void tower_out(
    const u16* __restrict__ th, const float* __restrict__ w2,
    const float* __restrict__ b2, float* __restrict__ out) {
  int r = blockIdx.x * 4 + (threadIdx.x >> 6);
  int lane = threadIdx.x & 63;
  int t = r / B_;
  const u16* row = th + (size_t)r * 256;
  u16 hv[4];
  *(uint2*)hv = *(const uint2*)(row + lane * 4);
  float4 wv = *(const float4*)(w2 + t * 256 + lane * 4);
  float s = bf2f(hv[0]) * wv.x + bf2f(hv[1]) * wv.y + bf2f(hv[2]) * wv.z + bf2f(hv[3]) * wv.w;
  for (int off = 32; off > 0; off >>= 1) s += __shfl_down(s, off, 64);
  if (lane == 0) out[r] = s + b2[t];
}

extern "C" void kernel_launch(void* const* d_in, const int* in_sizes, int n_in,
                              void* d_out, int out_size, void* d_ws, size_t ws_size,
                              hipStream_t stream) {
  (void)in_sizes; (void)n_in; (void)out_size;
  const float* x      = (const float*)d_in[0];
  const float* m_w1   = (const float*)d_in[1];
  const float* m_b1   = (const float*)d_in[2];
  const float* m_g    = (const float*)d_in[3];
  const float* m_be   = (const float*)d_in[4];
  const float* m_w2   = (const float*)d_in[5];
  const float* m_b2   = (const float*)d_in[6];
  const float* m_gw   = (const float*)d_in[7];
  const float* m_gb   = (const float*)d_in[8];
  const float* c0_sw1 = (const float*)d_in[9];
  const float* c0_sb1 = (const float*)d_in[10];
  const float* c0_sg  = (const float*)d_in[11];
  const float* c0_sbe = (const float*)d_in[12];
  const float* c0_sw2 = (const float*)d_in[13];
  const float* c0_sb2 = (const float*)d_in[14];
  const float* c0_tw1 = (const float*)d_in[15];
  const float* c0_tb1 = (const float*)d_in[16];
  const float* c0_tg  = (const float*)d_in[17];
  const float* c0_tbe = (const float*)d_in[18];
  const float* c0_tw2 = (const float*)d_in[19];
  const float* c0_tb2 = (const float*)d_in[20];
  const float* c0_gw  = (const float*)d_in[21];
  const float* c0_gb  = (const float*)d_in[22];
  const float* c0_sgw = (const float*)d_in[23];
  const float* c0_sgb = (const float*)d_in[24];
  const float* c1_sw1 = (const float*)d_in[25];
  const float* c1_sb1 = (const float*)d_in[26];
  const float* c1_sg  = (const float*)d_in[27];
  const float* c1_sbe = (const float*)d_in[28];
  const float* c1_sw2 = (const float*)d_in[29];
  const float* c1_sb2 = (const float*)d_in[30];
  const float* c1_tw1 = (const float*)d_in[31];
  const float* c1_tb1 = (const float*)d_in[32];
  const float* c1_tg  = (const float*)d_in[33];
  const float* c1_tbe = (const float*)d_in[34];
  const float* c1_tw2 = (const float*)d_in[35];
  const float* c1_tb2 = (const float*)d_in[36];
  const float* c1_gw  = (const float*)d_in[37];
  const float* c1_gb  = (const float*)d_in[38];
  const float* tw1    = (const float*)d_in[39];
  const float* tb1    = (const float*)d_in[40];
  const float* tw2    = (const float*)d_in[41];
  const float* tb2    = (const float*)d_in[42];

  // ---- static region layout (171 MB total, phase-aliased) ----
  const size_t MB = 1024 * 1024;
  char* ws = (char*)d_ws;
  size_t off = 0;
  u16* arena = (u16*)(ws + off); off += 24 * MB;   // transposed-weight arena (per phase)
  u16* eoR   = (u16*)(ws + off); off += 64 * MB;   // MMoE eo[8,B,512] | CGC so(16MB)+to(36MB)
  u16* hbuf  = (u16*)(ws + off); off += 32 * MB;   // expert hidden (1x[B,2048] or 2x[B,1024]) | tower th
  u16* thsR  = (u16*)(ws + off); off += 24 * MB;   // task_hs[3,B,512] | task2[3,B,256]
  u16* xbR   = (u16*)(ws + off); off += 16 * MB;   // xb[B,1024] | task1(12MB)+shared1(4MB)
  u16* shR   = (u16*)(ws + off); off += 8 * MB;    // shared_h[B,512]
  float* gmo = (float*)(ws + off); off += 3 * MB;  // gates: gmo|g0|sg0|g1
  if (ws_size < off) return;  // ws too small -> clean validation failure, not a fault

  float* g0  = gmo + (size_t)3 * B_ * 8;
  float* sg0 = g0  + (size_t)3 * B_ * 7;
  float* g1  = sg0 + (size_t)B_ * 13;

  u16* xb       = xbR;
  u16* eo       = eoR;
  u16* task_hs  = thsR;
  u16* shared_h = shR;
  u16* soD      = eoR;                             // [4,B,256] = 16 MB
  u16* toD      = eoR + (size_t)4 * B_ * 256;      // [9,B,256] = 36 MB
  u16* task1    = xbR;                             // [3,B,256] = 12 MB
  u16* shared1  = xbR + (size_t)3 * B_ * 256;      // [B,256]   =  4 MB
  u16* task2    = thsR;                            // [3,B,256] = 12 MB
  u16* thbuf    = hbuf;                            // [3,B,256] = 12 MB

  dim3 blk(256);
  cast_bf16k<<<8192, blk, 0, stream>>>(x, xb);
  gate_softmax<<<B_, blk, 0, stream>>>(x, 0, 0L, m_gw, m_gb, gmo, 3, 1024, 8, 8);

  // ---- MMoE: 4 groups of 2 experts (arena = 8MB w1t + 4MB w2t), per-expert hidden ----
  {
    u16* w1t = arena;                              // 2 x [2048][1024]
    u16* w2t = arena + (size_t)2 * 2048 * 1024;    // 2 x [512][2048]
    for (int gg = 0; gg < 4; ++gg) {
      transpose_cast<<<dim3(16, 32, 2), blk, 0, stream>>>(m_w1 + (size_t)gg * 2 * 1024 * 2048, w1t, 1024, 2048);
      transpose_cast<<<dim3(32,  8, 2), blk, 0, stream>>>(m_w2 + (size_t)gg * 2 * 2048 * 512,  w2t, 2048, 512);
      for (int e2 = 0; e2 < 2; ++e2) {
        int e = gg * 2 + e2;
        gemm_bf16<<<dim3(64, 16, 1), blk, 0, stream>>>(
            xb, 0L, 1, 0, w1t + (size_t)e2 * 2048 * 1024, m_b1 + (size_t)e * 2048, hbuf, 2048, 1024, 0);
        ln_affine_relu<<<B_, blk, 0, stream>>>(hbuf, m_g + (size_t)e * 2048, m_be + (size_t)e * 2048, 2048);
        gemm_bf16<<<dim3(64, 4, 1), blk, 0, stream>>>(
            hbuf, 0L, 1, 0, w2t + (size_t)e2 * 512 * 2048, m_b2 + (size_t)e * 512,
            eo + (size_t)e * B_ * 512, 512, 2048, 0);
      }
    }
  }
  mmoe_mix<<<B_, blk, 0, stream>>>(eo, gmo, task_hs, shared_h);

  // gates for CGC0 read task_hs / shared_h (before eoR is overwritten is fine; they don't touch eoR)
  gate_softmax<<<B_, blk, 0, stream>>>(task_hs, 1, (long)B_ * 512, c0_gw, c0_gb, g0, 3, 512, 7, 8);
  gate_softmax<<<B_, blk, 0, stream>>>(shared_h, 1, 0L, c0_sgw, c0_sgb, sg0, 1, 512, 13, 16);

  // ---- CGC layer 0 (arena: sw1t 4MB | sw2t 2MB | tw1t 9MB | tw2t 4.5MB) ----
  {
    u16* sw1t = arena;
    u16* sw2t = sw1t + (size_t)4 * 1024 * 512;
    u16* tw1t = sw2t + (size_t)4 * 256 * 1024;
    u16* tw2t = tw1t + (size_t)9 * 1024 * 512;
    transpose_cast<<<dim3( 8, 16, 4), blk, 0, stream>>>(c0_sw1, sw1t, 512, 1024);
    transpose_cast<<<dim3(16,  4, 4), blk, 0, stream>>>(c0_sw2, sw2t, 1024, 256);
    transpose_cast<<<dim3( 8, 16, 9), blk, 0, stream>>>(c0_tw1, tw1t, 512, 1024);
    transpose_cast<<<dim3(16,  4, 9), blk, 0, stream>>>(c0_tw2, tw2t, 1024, 256);
    for (int g0i = 0; g0i < 4; g0i += 2) {  // shared experts, groups of 2
      gemm_bf16<<<dim3(64, 8, 2), blk, 0, stream>>>(
          shared_h, 0L, 1, 0, sw1t + (size_t)g0i * 1024 * 512, c0_sb1 + (size_t)g0i * 1024, hbuf, 1024, 512, 0);
      ln_affine_relu<<<2 * B_, blk, 0, stream>>>(hbuf, c0_sg + (size_t)g0i * 1024, c0_sbe + (size_t)g0i * 1024, 1024);
      gemm_bf16<<<dim3(64, 2, 2), blk, 0, stream>>>(
          hbuf, (long)B_ * 1024, 1, 0, sw2t + (size_t)g0i * 256 * 1024, c0_sb2 + (size_t)g0i * 256,
          soD + (size_t)g0i * B_ * 256, 256, 1024, 0);
    }
    for (int g0i = 0; g0i < 9; g0i += 2) {  // task experts, groups of 2 (+1 single)
      int gsz = (g0i + 2 <= 9) ? 2 : 1;
      gemm_bf16<<<dim3(64, 8, gsz), blk, 0, stream>>>(
          task_hs, (long)B_ * 512, 3, g0i, tw1t + (size_t)g0i * 1024 * 512, c0_tb1 + (size_t)g0i * 1024,
          hbuf, 1024, 512, 0);
      ln_affine_relu<<<gsz * B_, blk, 0, stream>>>(hbuf, c0_tg + (size_t)g0i * 1024, c0_tbe + (size_t)g0i * 1024, 1024);
      gemm_bf16<<<dim3(64, 2, gsz), blk, 0, stream>>>(
          hbuf, (long)B_ * 1024, 1, 0, tw2t + (size_t)g0i * 256 * 1024, c0_tb2 + (size_t)g0i * 256,
          toD + (size_t)g0i * B_ * 256, 256, 1024, 0);
    }
  }
  cgc_mix<<<B_, blk, 0, stream>>>(toD, soD, g0, sg0, task1, shared1);
  gate_softmax<<<B_, blk, 0, stream>>>(task1, 1, (long)B_ * 256, c1_gw, c1_gb, g1, 3, 256, 7, 8);

  // ---- CGC layer 1 (arena: sw1t 2MB | sw2t 2MB | tw1t 4.5MB | tw2t 4.5MB) ----
  {
    u16* sw1t = arena;
    u16* sw2t = sw1t + (size_t)4 * 1024 * 256;
    u16* tw1t = sw2t + (size_t)4 * 256 * 1024;
    u16* tw2t = tw1t + (size_t)9 * 1024 * 256;
    transpose_cast<<<dim3( 4, 16, 4), blk, 0, stream>>>(c1_sw1, sw1t, 256, 1024);
    transpose_cast<<<dim3(16,  4, 4), blk, 0, stream>>>(c1_sw2, sw2t, 1024, 256);
    transpose_cast<<<dim3( 4, 16, 9), blk, 0, stream>>>(c1_tw1, tw1t, 256, 1024);
    transpose_cast<<<dim3(16,  4, 9), blk, 0, stream>>>(c1_tw2, tw2t, 1024, 256);
    for (int g0i = 0; g0i < 4; g0i += 2) {
      gemm_bf16<<<dim3(64, 8, 2), blk, 0, stream>>>(
          shared1, 0L, 1, 0, sw1t + (size_t)g0i * 1024 * 256, c1_sb1 + (size_t)g0i * 1024, hbuf, 1024, 256, 0);
      ln_affine_relu<<<2 * B_, blk, 0, stream>>>(hbuf, c1_sg + (size_t)g0i * 1024, c1_sbe + (size_t)g0i * 1024, 1024);
      gemm_bf16<<<dim3(64, 2, 2), blk, 0, stream>>>(
          hbuf, (long)B_ * 1024, 1, 0, sw2t + (size_t)g0i * 256 * 1024, c1_sb2 + (size_t)g0i * 256,
          soD + (size_t)g0i * B_ * 256, 256, 1024, 0);
    }
    for (int g0i = 0; g0i < 9; g0i += 2) {
      int gsz = (g0i + 2 <= 9) ? 2 : 1;
      gemm_bf16<<<dim3(64, 8, gsz), blk, 0, stream>>>(
          task1, (long)B_ * 256, 3, g0i, tw1t + (size_t)g0i * 1024 * 256, c1_tb1 + (size_t)g0i * 1024,
          hbuf, 1024, 256, 0);
      ln_affine_relu<<<gsz * B_, blk, 0, stream>>>(hbuf, c1_tg + (size_t)g0i * 1024, c1_tbe + (size_t)g0i * 1024, 1024);
      gemm_bf16<<<dim3(64, 2, gsz), blk, 0, stream>>>(
          hbuf, (long)B_ * 1024, 1, 0, tw2t + (size_t)g0i * 256 * 1024, c1_tb2 + (size_t)g0i * 256,
          toD + (size_t)g0i * B_ * 256, 256, 1024, 0);
    }
  }
  cgc_mix<<<B_, blk, 0, stream>>>(toD, soD, g1, nullptr, task2, nullptr);

  // ---- towers (arena: tw1t 0.375MB) ----
  {
    u16* twt = arena;
    transpose_cast<<<dim3(4, 4, 3), blk, 0, stream>>>(tw1, twt, 256, 256);
    gemm_bf16<<<dim3(64, 2, 3), blk, 0, stream>>>(task2, (long)B_ * 256, 1, 0, twt, tb1, thbuf, 256, 256, 1);
    tower_out<<<6144, blk, 0, stream>>>(thbuf, tw2, tb2, (float*)d_out);
  }
}

// Round 3
// 2373.841 us; speedup vs baseline: 1.3709x; 1.3709x over previous
//
#include <hip/hip_runtime.h>

typedef unsigned short u16;
typedef unsigned int   u32;
typedef __bf16  bf16x8 __attribute__((ext_vector_type(8)));
typedef float   f32x4  __attribute__((ext_vector_type(4)));

#define B_ 8192
#define DI __device__ __forceinline__

DI u16 f2bf(float f) {
  u32 u = __float_as_uint(f);
  u = (u + 0x7fffu + ((u >> 16) & 1u)) >> 16;   // RNE
  return (u16)u;
}
DI float bf2f(u16 h) { return __uint_as_float(((u32)h) << 16); }

// async global->LDS, 16B per lane; LDS dest = wave-uniform base + lane*16
DI void gll(const u16* g, u16* l) {
  __builtin_amdgcn_global_load_lds(
      (const __attribute__((address_space(1))) void*)g,
      (__attribute__((address_space(3))) void*)l, 16, 0, 0);
}

// ---------------- weight transpose + cast: W[g][K][N] f32 -> Wt[g][N][K] bf16
__global__ __launch_bounds__(256) void transpose_cast(
    const float* __restrict__ W, u16* __restrict__ Wt, int K, int N) {
  __shared__ float tile[64][65];
  int g = blockIdx.z;
  int k0 = blockIdx.x * 64, n0 = blockIdx.y * 64;
  const float* Wg = W + (size_t)g * K * N;
  u16* Og = Wt + (size_t)g * N * K;
  int tid = threadIdx.x;
  int rr = tid >> 4, cc = (tid & 15) * 4;
#pragma unroll
  for (int r = 0; r < 4; ++r) {
    int k = rr + r * 16;
    float4 v = *(const float4*)(Wg + (size_t)(k0 + k) * N + n0 + cc);
    tile[k][cc] = v.x; tile[k][cc + 1] = v.y; tile[k][cc + 2] = v.z; tile[k][cc + 3] = v.w;
  }
  __syncthreads();
  int nr = tid >> 3, kc = (tid & 7) * 8;
#pragma unroll
  for (int p = 0; p < 2; ++p) {
    int n = nr + p * 32;
    u16 tmp[8];
#pragma unroll
    for (int j = 0; j < 8; ++j) tmp[j] = f2bf(tile[kc + j][n]);
    *(uint4*)(Og + (size_t)(n0 + n) * K + k0 + kc) = *(uint4*)tmp;
  }
}

// ---------------- f32 -> bf16 cast (4 elems/thread)
__global__ __launch_bounds__(256) void cast_bf16k(const float* __restrict__ X, u16* __restrict__ Y) {
  size_t i = ((size_t)blockIdx.x * 256 + threadIdx.x) * 4;
  float4 v = *(const float4*)(X + i);
  u16 t[4] = { f2bf(v.x), f2bf(v.y), f2bf(v.z), f2bf(v.w) };
  *(uint2*)(Y + i) = *(uint2*)t;
}

// ---------------- batched bf16 GEMM with global_load_lds staging (m97 structure)
#define BM 128
#define BN 128
#define BK 32
#define LDK 32   // unpadded: required by global_load_lds lane mapping

__global__ __launch_bounds__(256) void gemm_bf16(
    const u16* __restrict__ A, long a_stride, int a_div, int a_g0,
    const u16* __restrict__ Wt, const float* __restrict__ bias,
    u16* __restrict__ C, int N, int K, int relu_flag) {
  int gz = blockIdx.z;
  const u16* Ag = A + (size_t)((a_g0 + gz) / a_div) * a_stride;
  const u16* Wg = Wt + (size_t)gz * N * K;
  u16* Cg = C + (size_t)gz * B_ * N;
  int m0 = blockIdx.x * BM, n0 = blockIdx.y * BN;

  __shared__ __align__(16) u16 As[BM * LDK];
  __shared__ __align__(16) u16 Bs[BN * LDK];

  int tid = threadIdx.x;
  int wv = tid >> 6, ln = tid & 63;
  int wm = (wv >> 1) * 64, wn = (wv & 1) * 64;
  int lr = ln & 15, lk = (ln >> 4) * 8;

  // staging map: wave wv covers rows [32*wv, 32*wv+32), 2 issues of 16 rows
  int sr = ln >> 2;           // 0..15
  int sc = (ln & 3) * 8;      // u16 col 0,8,16,24
  const u16* aG = Ag + (size_t)(m0 + wv * 32 + sr) * K + sc;
  const u16* bG = Wg + (size_t)(n0 + wv * 32 + sr) * K + sc;
  u16* aL0 = As + (wv * 32) * LDK;
  u16* aL1 = aL0 + 16 * LDK;
  u16* bL0 = Bs + (wv * 32) * LDK;
  u16* bL1 = bL0 + 16 * LDK;

  f32x4 acc[4][4];
#pragma unroll
  for (int i = 0; i < 4; ++i)
#pragma unroll
    for (int j = 0; j < 4; ++j)
      acc[i][j] = (f32x4){0.f, 0.f, 0.f, 0.f};

  int nk = K / BK;
  for (int ks = 0; ks < nk; ++ks) {
    __syncthreads();                       // prev ds_reads done before overwrite
    gll(aG + ks * BK, aL0);
    gll(aG + ks * BK + (size_t)16 * K, aL1);
    gll(bG + ks * BK, bL0);
    gll(bG + ks * BK + (size_t)16 * K, bL1);
    __syncthreads();                       // drains vmcnt before barrier
    bf16x8 af[4], bfr[4];
#pragma unroll
    for (int i = 0; i < 4; ++i) {
      union { uint4 u; bf16x8 v; } ua, ub;
      ua.u = *(const uint4*)(As + (wm + i * 16 + lr) * LDK + lk);
      ub.u = *(const uint4*)(Bs + (wn + i * 16 + lr) * LDK + lk);
      af[i] = ua.v; bfr[i] = ub.v;
    }
#pragma unroll
    for (int i = 0; i < 4; ++i)
#pragma unroll
      for (int j = 0; j < 4; ++j)
        acc[i][j] = __builtin_amdgcn_mfma_f32_16x16x32_bf16(af[i], bfr[j], acc[i][j], 0, 0, 0);
  }

  // epilogue: D row = (lane>>4)*4+reg, col = lane&15
  int mr = (ln >> 4) * 4;
#pragma unroll
  for (int i = 0; i < 4; ++i) {
#pragma unroll
    for (int j = 0; j < 4; ++j) {
      int n = n0 + wn + j * 16 + lr;
      float bv = bias[(size_t)gz * N + n];
#pragma unroll
      for (int r = 0; r < 4; ++r) {
        int m = m0 + wm + i * 16 + mr + r;
        float v = acc[i][j][r] + bv;
        if (relu_flag) v = fmaxf(v, 0.f);
        Cg[(size_t)m * N + n] = f2bf(v);
      }
    }
  }
}

// ---------------- rowwise LayerNorm * gain + beta, ReLU, in-place on bf16
// launch with blockDim = N/8 (128 or 256); gain/beta pre-offset; grp = row/B_
__global__ __launch_bounds__(256) void ln_affine_relu(
    u16* __restrict__ H, const float* __restrict__ gain, const float* __restrict__ beta, int N) {
  __shared__ float red[4];
  size_t row = blockIdx.x;
  int grp = (int)(row / B_);
  u16* hp = H + row * N;
  const float* gp = gain + (size_t)grp * N;
  const float* bp = beta + (size_t)grp * N;
  int tid = threadIdx.x;
  int nw = blockDim.x >> 6;
  union { uint4 u; u16 s[8]; } pk;
  pk.u = *(const uint4*)(hp + tid * 8);
  float v[8], s = 0.f;
#pragma unroll
  for (int j = 0; j < 8; ++j) { v[j] = bf2f(pk.s[j]); s += v[j]; }
  for (int off = 32; off > 0; off >>= 1) s += __shfl_down(s, off, 64);
  if ((tid & 63) == 0) red[tid >> 6] = s;
  __syncthreads();
  float tot = 0.f;
  for (int i = 0; i < nw; ++i) tot += red[i];
  float mu = tot / (float)N;
  float q = 0.f;
#pragma unroll
  for (int j = 0; j < 8; ++j) { float d = v[j] - mu; q += d * d; }
  __syncthreads();
  for (int off = 32; off > 0; off >>= 1) q += __shfl_down(q, off, 64);
  if ((tid & 63) == 0) red[tid >> 6] = q;
  __syncthreads();
  tot = 0.f;
  for (int i = 0; i < nw; ++i) tot += red[i];
  float rstd = rsqrtf(tot / (float)N + 1e-5f);
  float4 ga = *(const float4*)(gp + tid * 8);
  float4 gb2 = *(const float4*)(gp + tid * 8 + 4);
  float4 ba = *(const float4*)(bp + tid * 8);
  float4 bb2 = *(const float4*)(bp + tid * 8 + 4);
  float gg[8] = { ga.x, ga.y, ga.z, ga.w, gb2.x, gb2.y, gb2.z, gb2.w };
  float bt[8] = { ba.x, ba.y, ba.z, ba.w, bb2.x, bb2.y, bb2.z, bb2.w };
  u16 o[8];
#pragma unroll
  for (int j = 0; j < 8; ++j) {
    float y = (v[j] - mu) * rstd * gg[j] + bt[j];
    o[j] = f2bf(fmaxf(y, 0.f));
  }
  *(uint4*)(hp + tid * 8) = *(uint4*)o;
}

// ---------------- pack gate weights: W[t][k][e] -> out4[k4][j][0..3], j=t*L+e
__global__ __launch_bounds__(256) void prep_gw4(
    const float* __restrict__ W, float* __restrict__ out4,
    int G, int K, int E, int L) {
  int id = blockIdx.x * 256 + threadIdx.x;
  int tot = (K >> 2) * 32;
  if (id >= tot) return;
  int k4 = id >> 5, j = id & 31;
  int t = j / L, e = j % L;
  float4 v = { 0.f, 0.f, 0.f, 0.f };
  if (t < G && e < E) {
    const float* w = W + (size_t)t * K * E + e;
    v.x = w[(size_t)(k4 * 4 + 0) * E];
    v.y = w[(size_t)(k4 * 4 + 1) * E];
    v.z = w[(size_t)(k4 * 4 + 2) * E];
    v.w = w[(size_t)(k4 * 4 + 3) * E];
  }
  *(float4*)(out4 + (size_t)id * 4) = v;
}

// ---------------- fast gates: 8 rows/block, lane j=t*L+e, coalesced fp32 math
__global__ __launch_bounds__(256) void gates_fast(
    const void* __restrict__ X, int is_bf16, long t_stride,
    const float* __restrict__ GW4, const float* __restrict__ GB,
    float* __restrict__ out, int G, int K, int E, int L) {
  int tid = threadIdx.x;
  int rl = tid >> 5;             // row within block, 0..7
  int j  = tid & 31;
  int t = j / L, e = j % L;
  int b = blockIdx.x * 8 + rl;
  int tr = (t < G) ? t : (G - 1);   // clamp for safe loads on dead lanes
  float acc = 0.f;
  int K4 = K >> 2;
  if (is_bf16) {
    const u16* xr = (const u16*)X + (size_t)tr * t_stride + (size_t)b * K;
    for (int k4 = 0; k4 < K4; ++k4) {
      uint2 p = *(const uint2*)(xr + k4 * 4);
      float4 g4 = *(const float4*)(GW4 + ((size_t)k4 * 32 + j) * 4);
      acc += bf2f((u16)(p.x & 0xffffu)) * g4.x + bf2f((u16)(p.x >> 16)) * g4.y
           + bf2f((u16)(p.y & 0xffffu)) * g4.z + bf2f((u16)(p.y >> 16)) * g4.w;
    }
  } else {
    const float* xr = (const float*)X + (size_t)tr * t_stride + (size_t)b * K;
    for (int k4 = 0; k4 < K4; ++k4) {
      float4 xv = *(const float4*)(xr + k4 * 4);
      float4 g4 = *(const float4*)(GW4 + ((size_t)k4 * 32 + j) * 4);
      acc += xv.x * g4.x + xv.y * g4.y + xv.z * g4.z + xv.w * g4.w;
    }
  }
  bool valid = (t < G) && (e < E);
  float lg = valid ? (acc + GB[t * E + e]) : -1e30f;
  float m = lg;
  for (int o = L >> 1; o > 0; o >>= 1) m = fmaxf(m, __shfl_xor(m, o, L));
  float ex = valid ? expf(lg - m) : 0.f;
  float sm = ex;
  for (int o = L >> 1; o > 0; o >>= 1) sm += __shfl_xor(sm, o, L);
  if (valid) out[((size_t)t * B_ + b) * E + e] = ex / sm;
}

// ---------------- MMoE mixing: task_hs[t]=sum_e g[t,e]*eo[e]; shared=mean_t
__global__ __launch_bounds__(256) void mmoe_mix(
    const u16* __restrict__ eo, const float* __restrict__ gates,
    u16* __restrict__ task_hs, u16* __restrict__ shared_h) {
  __shared__ float g[24];
  int b = blockIdx.x, tid = threadIdx.x;
  if (tid < 24) g[tid] = gates[((size_t)(tid >> 3) * B_ + b) * 8 + (tid & 7)];
  __syncthreads();
  int o = tid * 2;
  float a0[3] = {0, 0, 0}, a1[3] = {0, 0, 0};
#pragma unroll
  for (int e = 0; e < 8; ++e) {
    u32 w = *(const u32*)(eo + ((size_t)e * B_ + b) * 512 + o);
    float v0 = bf2f((u16)(w & 0xffffu)), v1 = bf2f((u16)(w >> 16));
#pragma unroll
    for (int t = 0; t < 3; ++t) { a0[t] += g[t * 8 + e] * v0; a1[t] += g[t * 8 + e] * v1; }
  }
  float s0 = 0.f, s1 = 0.f;
#pragma unroll
  for (int t = 0; t < 3; ++t) {
    u16 p[2] = { f2bf(a0[t]), f2bf(a1[t]) };
    *(u32*)(task_hs + ((size_t)t * B_ + b) * 512 + o) = *(u32*)p;
    s0 += a0[t]; s1 += a1[t];
  }
  u16 p[2] = { f2bf(s0 * (1.f / 3.f)), f2bf(s1 * (1.f / 3.f)) };
  *(u32*)(shared_h + (size_t)b * 512 + o) = *(u32*)p;
}

// ---------------- CGC mixing (task experts first, then shared; opt shared-gate out)
__global__ __launch_bounds__(256) void cgc_mix(
    const u16* __restrict__ to, const u16* __restrict__ so,
    const float* __restrict__ g, const float* __restrict__ sg,
    u16* __restrict__ task_out, u16* __restrict__ shared_out) {
  int b = blockIdx.x, o = threadIdx.x;
  float tv[9], sv[4];
#pragma unroll
  for (int j = 0; j < 9; ++j) tv[j] = bf2f(to[((size_t)j * B_ + b) * 256 + o]);
#pragma unroll
  for (int s = 0; s < 4; ++s) sv[s] = bf2f(so[((size_t)s * B_ + b) * 256 + o]);
#pragma unroll
  for (int t = 0; t < 3; ++t) {
    const float* gt = g + ((size_t)t * B_ + b) * 7;
    float a = gt[0] * tv[t * 3] + gt[1] * tv[t * 3 + 1] + gt[2] * tv[t * 3 + 2];
#pragma unroll
    for (int s = 0; s < 4; ++s) a += gt[3 + s] * sv[s];
    task_out[((size_t)t * B_ + b) * 256 + o] = f2bf(a);
  }
  if (shared_out) {
    const float* sp = sg + (size_t)b * 13;
    float a = 0.f;
#pragma unroll
    for (int j = 0; j < 9; ++j) a += sp[j] * tv[j];
#pragma unroll
    for (int s = 0; s < 4; ++s) a += sp[9 + s] * sv[s];
    shared_out[(size_t)b * 256 + o] = f2bf(a);
  }
}

// ---------------- tower head: out[t*B+b] = th[t,b,:] . w2[t,:] + b2[t]  (fp32 out)
__global__ __launch_bounds__(256) void tower_out(
    const u16* __restrict__ th, const float* __restrict__ w2,
    const float* __restrict__ b2, float* __restrict__ out) {
  int r = blockIdx.x * 4 + (threadIdx.x >> 6);
  int lane = threadIdx.x & 63;
  int t = r / B_;
  const u16* row = th + (size_t)r * 256;
  u16 hv[4];
  *(uint2*)hv = *(const uint2*)(row + lane * 4);
  float4 wv = *(const float4*)(w2 + t * 256 + lane * 4);
  float s = bf2f(hv[0]) * wv.x + bf2f(hv[1]) * wv.y + bf2f(hv[2]) * wv.z + bf2f(hv[3]) * wv.w;
  for (int off = 32; off > 0; off >>= 1) s += __shfl_down(s, off, 64);
  if (lane == 0) out[r] = s + b2[t];
}

extern "C" void kernel_launch(void* const* d_in, const int* in_sizes, int n_in,
                              void* d_out, int out_size, void* d_ws, size_t ws_size,
                              hipStream_t stream) {
  (void)in_sizes; (void)n_in; (void)out_size;
  const float* x      = (const float*)d_in[0];
  const float* m_w1   = (const float*)d_in[1];
  const float* m_b1   = (const float*)d_in[2];
  const float* m_g    = (const float*)d_in[3];
  const float* m_be   = (const float*)d_in[4];
  const float* m_w2   = (const float*)d_in[5];
  const float* m_b2   = (const float*)d_in[6];
  const float* m_gw   = (const float*)d_in[7];
  const float* m_gb   = (const float*)d_in[8];
  const float* c0_sw1 = (const float*)d_in[9];
  const float* c0_sb1 = (const float*)d_in[10];
  const float* c0_sg  = (const float*)d_in[11];
  const float* c0_sbe = (const float*)d_in[12];
  const float* c0_sw2 = (const float*)d_in[13];
  const float* c0_sb2 = (const float*)d_in[14];
  const float* c0_tw1 = (const float*)d_in[15];
  const float* c0_tb1 = (const float*)d_in[16];
  const float* c0_tg  = (const float*)d_in[17];
  const float* c0_tbe = (const float*)d_in[18];
  const float* c0_tw2 = (const float*)d_in[19];
  const float* c0_tb2 = (const float*)d_in[20];
  const float* c0_gw  = (const float*)d_in[21];
  const float* c0_gb  = (const float*)d_in[22];
  const float* c0_sgw = (const float*)d_in[23];
  const float* c0_sgb = (const float*)d_in[24];
  const float* c1_sw1 = (const float*)d_in[25];
  const float* c1_sb1 = (const float*)d_in[26];
  const float* c1_sg  = (const float*)d_in[27];
  const float* c1_sbe = (const float*)d_in[28];
  const float* c1_sw2 = (const float*)d_in[29];
  const float* c1_sb2 = (const float*)d_in[30];
  const float* c1_tw1 = (const float*)d_in[31];
  const float* c1_tb1 = (const float*)d_in[32];
  const float* c1_tg  = (const float*)d_in[33];
  const float* c1_tbe = (const float*)d_in[34];
  const float* c1_tw2 = (const float*)d_in[35];
  const float* c1_tb2 = (const float*)d_in[36];
  const float* c1_gw  = (const float*)d_in[37];
  const float* c1_gb  = (const float*)d_in[38];
  const float* tw1    = (const float*)d_in[39];
  const float* tb1    = (const float*)d_in[40];
  const float* tw2    = (const float*)d_in[41];
  const float* tb2    = (const float*)d_in[42];

  // ---- static region layout (171 MB total, phase-aliased) ----
  const size_t MB = 1024 * 1024;
  char* ws = (char*)d_ws;
  size_t off = 0;
  u16* arena = (u16*)(ws + off); off += 24 * MB;   // transposed-weight arena (per phase)
  u16* eoR   = (u16*)(ws + off); off += 64 * MB;   // MMoE eo[8,B,512] | CGC so+to
  u16* hbuf  = (u16*)(ws + off); off += 32 * MB;   // gw4 packs (pre-GEMM) | expert hidden | tower th
  u16* thsR  = (u16*)(ws + off); off += 24 * MB;   // MMoE wT groups 2-3 | task_hs | task2
  u16* xbR   = (u16*)(ws + off); off += 16 * MB;   // xb | task1+shared1
  u16* shR   = (u16*)(ws + off); off += 8 * MB;    // shared_h
  float* gmo = (float*)(ws + off); off += 3 * MB;  // gates out: gmo|g0|sg0|g1
  if (ws_size < off) return;

  float* g0  = gmo + (size_t)3 * B_ * 8;
  float* sg0 = g0  + (size_t)3 * B_ * 7;
  float* g1  = sg0 + (size_t)B_ * 13;

  u16* xb       = xbR;
  u16* eo       = eoR;
  u16* task_hs  = thsR;
  u16* shared_h = shR;
  u16* soD      = eoR;                             // [4,B,256]
  u16* toD      = eoR + (size_t)4 * B_ * 256;      // [9,B,256]
  u16* task1    = xbR;                             // [3,B,256]
  u16* shared1  = xbR + (size_t)3 * B_ * 256;      // [B,256]
  u16* task2    = thsR;                            // [3,B,256]
  u16* thbuf    = hbuf;                            // [3,B,256]

  // gate-weight packs live at the front of hbuf (used strictly before GEMMs write it)
  float* gw4a = (float*)hbuf;          // up to 128 KB
  float* gw4b = (float*)hbuf + 32768;  // second 128 KB slot

  dim3 blk(256);
  cast_bf16k<<<8192, blk, 0, stream>>>(x, xb);

  // ---- MMoE gate (fp32, coalesced) ----
  prep_gw4<<<32, blk, 0, stream>>>(m_gw, gw4a, 3, 1024, 8, 8);
  gates_fast<<<B_ / 8, blk, 0, stream>>>(x, 0, 0L, gw4a, m_gb, gmo, 3, 1024, 8, 8);

  // ---- MMoE weights: all 8 experts transposed upfront (arena: e0-3, thsR: e4-7) ----
  {
    u16* w1t_lo = arena;                                // 4 x [2048][1024] = 16 MB
    u16* w2t_lo = arena + (size_t)4 * 2048 * 1024;      // 4 x [512][2048]  =  8 MB
    u16* w1t_hi = thsR;
    u16* w2t_hi = thsR + (size_t)4 * 2048 * 1024;
    transpose_cast<<<dim3(16, 32, 4), blk, 0, stream>>>(m_w1, w1t_lo, 1024, 2048);
    transpose_cast<<<dim3(32,  8, 4), blk, 0, stream>>>(m_w2, w2t_lo, 2048, 512);
    transpose_cast<<<dim3(16, 32, 4), blk, 0, stream>>>(m_w1 + (size_t)4 * 1024 * 2048, w1t_hi, 1024, 2048);
    transpose_cast<<<dim3(32,  8, 4), blk, 0, stream>>>(m_w2 + (size_t)4 * 2048 * 512,  w2t_hi, 2048, 512);
    for (int e = 0; e < 8; ++e) {
      u16* w1t = (e < 4 ? w1t_lo : w1t_hi) + (size_t)(e & 3) * 2048 * 1024;
      u16* w2t = (e < 4 ? w2t_lo : w2t_hi) + (size_t)(e & 3) * 512 * 2048;
      gemm_bf16<<<dim3(64, 16, 1), blk, 0, stream>>>(
          xb, 0L, 1, 0, w1t, m_b1 + (size_t)e * 2048, hbuf, 2048, 1024, 0);
      ln_affine_relu<<<B_, 256, 0, stream>>>(hbuf, m_g + (size_t)e * 2048, m_be + (size_t)e * 2048, 2048);
      gemm_bf16<<<dim3(64, 4, 1), blk, 0, stream>>>(
          hbuf, 0L, 1, 0, w2t, m_b2 + (size_t)e * 512,
          eo + (size_t)e * B_ * 512, 512, 2048, 0);
    }
  }
  mmoe_mix<<<B_, blk, 0, stream>>>(eo, gmo, task_hs, shared_h);  // overwrites thsR — MMoE GEMMs done

  // ---- CGC0 gates (hbuf free again until CGC0 GEMMs) ----
  prep_gw4<<<16, blk, 0, stream>>>(c0_gw, gw4a, 3, 512, 7, 8);
  prep_gw4<<<16, blk, 0, stream>>>(c0_sgw, gw4b, 1, 512, 13, 16);
  gates_fast<<<B_ / 8, blk, 0, stream>>>(task_hs, 1, (long)B_ * 512, gw4a, c0_gb, g0, 3, 512, 7, 8);
  gates_fast<<<B_ / 8, blk, 0, stream>>>(shared_h, 1, 0L, gw4b, c0_sgb, sg0, 1, 512, 13, 16);

  // ---- CGC layer 0 (arena: sw1t 4MB | sw2t 2MB | tw1t 9MB | tw2t 4.5MB) ----
  {
    u16* sw1t = arena;
    u16* sw2t = sw1t + (size_t)4 * 1024 * 512;
    u16* tw1t = sw2t + (size_t)4 * 256 * 1024;
    u16* tw2t = tw1t + (size_t)9 * 1024 * 512;
    transpose_cast<<<dim3( 8, 16, 4), blk, 0, stream>>>(c0_sw1, sw1t, 512, 1024);
    transpose_cast<<<dim3(16,  4, 4), blk, 0, stream>>>(c0_sw2, sw2t, 1024, 256);
    transpose_cast<<<dim3( 8, 16, 9), blk, 0, stream>>>(c0_tw1, tw1t, 512, 1024);
    transpose_cast<<<dim3(16,  4, 9), blk, 0, stream>>>(c0_tw2, tw2t, 1024, 256);
    for (int g0i = 0; g0i < 4; g0i += 2) {
      gemm_bf16<<<dim3(64, 8, 2), blk, 0, stream>>>(
          shared_h, 0L, 1, 0, sw1t + (size_t)g0i * 1024 * 512, c0_sb1 + (size_t)g0i * 1024, hbuf, 1024, 512, 0);
      ln_affine_relu<<<2 * B_, 128, 0, stream>>>(hbuf, c0_sg + (size_t)g0i * 1024, c0_sbe + (size_t)g0i * 1024, 1024);
      gemm_bf16<<<dim3(64, 2, 2), blk, 0, stream>>>(
          hbuf, (long)B_ * 1024, 1, 0, sw2t + (size_t)g0i * 256 * 1024, c0_sb2 + (size_t)g0i * 256,
          soD + (size_t)g0i * B_ * 256, 256, 1024, 0);
    }
    for (int g0i = 0; g0i < 9; g0i += 2) {
      int gsz = (g0i + 2 <= 9) ? 2 : 1;
      gemm_bf16<<<dim3(64, 8, gsz), blk, 0, stream>>>(
          task_hs, (long)B_ * 512, 3, g0i, tw1t + (size_t)g0i * 1024 * 512, c0_tb1 + (size_t)g0i * 1024,
          hbuf, 1024, 512, 0);
      ln_affine_relu<<<gsz * B_, 128, 0, stream>>>(hbuf, c0_tg + (size_t)g0i * 1024, c0_tbe + (size_t)g0i * 1024, 1024);
      gemm_bf16<<<dim3(64, 2, gsz), blk, 0, stream>>>(
          hbuf, (long)B_ * 1024, 1, 0, tw2t + (size_t)g0i * 256 * 1024, c0_tb2 + (size_t)g0i * 256,
          toD + (size_t)g0i * B_ * 256, 256, 1024, 0);
    }
  }
  cgc_mix<<<B_, blk, 0, stream>>>(toD, soD, g0, sg0, task1, shared1);

  // ---- CGC1 gate ----
  prep_gw4<<<8, blk, 0, stream>>>(c1_gw, gw4a, 3, 256, 7, 8);
  gates_fast<<<B_ / 8, blk, 0, stream>>>(task1, 1, (long)B_ * 256, gw4a, c1_gb, g1, 3, 256, 7, 8);

  // ---- CGC layer 1 (arena: sw1t 2MB | sw2t 2MB | tw1t 4.5MB | tw2t 4.5MB) ----
  {
    u16* sw1t = arena;
    u16* sw2t = sw1t + (size_t)4 * 1024 * 256;
    u16* tw1t = sw2t + (size_t)4 * 256 * 1024;
    u16* tw2t = tw1t + (size_t)9 * 1024 * 256;
    transpose_cast<<<dim3( 4, 16, 4), blk, 0, stream>>>(c1_sw1, sw1t, 256, 1024);
    transpose_cast<<<dim3(16,  4, 4), blk, 0, stream>>>(c1_sw2, sw2t, 1024, 256);
    transpose_cast<<<dim3( 4, 16, 9), blk, 0, stream>>>(c1_tw1, tw1t, 256, 1024);
    transpose_cast<<<dim3(16,  4, 9), blk, 0, stream>>>(c1_tw2, tw2t, 1024, 256);
    for (int g0i = 0; g0i < 4; g0i += 2) {
      gemm_bf16<<<dim3(64, 8, 2), blk, 0, stream>>>(
          shared1, 0L, 1, 0, sw1t + (size_t)g0i * 1024 * 256, c1_sb1 + (size_t)g0i * 1024, hbuf, 1024, 256, 0);
      ln_affine_relu<<<2 * B_, 128, 0, stream>>>(hbuf, c1_sg + (size_t)g0i * 1024, c1_sbe + (size_t)g0i * 1024, 1024);
      gemm_bf16<<<dim3(64, 2, 2), blk, 0, stream>>>(
          hbuf, (long)B_ * 1024, 1, 0, sw2t + (size_t)g0i * 256 * 1024, c1_sb2 + (size_t)g0i * 256,
          soD + (size_t)g0i * B_ * 256, 256, 1024, 0);
    }
    for (int g0i = 0; g0i < 9; g0i += 2) {
      int gsz = (g0i + 2 <= 9) ? 2 : 1;
      gemm_bf16<<<dim3(64, 8, gsz), blk, 0, stream>>>(
          task1, (long)B_ * 256, 3, g0i, tw1t + (size_t)g0i * 1024 * 256, c1_tb1 + (size_t)g0i * 1024,
          hbuf, 1024, 256, 0);
      ln_affine_relu<<<gsz * B_, 128, 0, stream>>>(hbuf, c1_tg + (size_t)g0i * 1024, c1_tbe + (size_t)g0i * 1024, 1024);
      gemm_bf16<<<dim3(64, 2, gsz), blk, 0, stream>>>(
          hbuf, (long)B_ * 1024, 1, 0, tw2t + (size_t)g0i * 256 * 1024, c1_tb2 + (size_t)g0i * 256,
          toD + (size_t)g0i * B_ * 256, 256, 1024, 0);
    }
  }
  cgc_mix<<<B_, blk, 0, stream>>>(toD, soD, g1, nullptr, task2, nullptr);

  // ---- towers ----
  {
    u16* twt = arena;
    transpose_cast<<<dim3(4, 4, 3), blk, 0, stream>>>(tw1, twt, 256, 256);
    gemm_bf16<<<dim3(64, 2, 3), blk, 0, stream>>>(task2, (long)B_ * 256, 1, 0, twt, tb1, thbuf, 256, 256, 1);
    tower_out<<<6144, blk, 0, stream>>>(thbuf, tw2, tb2, (float*)d_out);
  }
}

// Round 4
// 2226.642 us; speedup vs baseline: 1.4616x; 1.0661x over previous
//
#include <hip/hip_runtime.h>

typedef unsigned short u16;
typedef unsigned int   u32;
typedef __bf16  bf16x8 __attribute__((ext_vector_type(8)));
typedef float   f32x4  __attribute__((ext_vector_type(4)));

#define B_ 8192
#define DI __device__ __forceinline__

DI u16 f2bf(float f) {
  u32 u = __float_as_uint(f);
  u = (u + 0x7fffu + ((u >> 16) & 1u)) >> 16;   // RNE
  return (u16)u;
}
DI float bf2f(u16 h) { return __uint_as_float(((u32)h) << 16); }

// async global->LDS, 16B per lane; LDS dest = wave-uniform base + lane*16
DI void gll(const u16* g, u16* l) {
  __builtin_amdgcn_global_load_lds(
      (const __attribute__((address_space(1))) void*)g,
      (__attribute__((address_space(3))) void*)l, 16, 0, 0);
}

// ---------------- weight transpose + cast: W[g][K][N] f32 -> Wt[g][N][K] bf16
__global__ __launch_bounds__(256) void transpose_cast(
    const float* __restrict__ W, u16* __restrict__ Wt, int K, int N) {
  __shared__ float tile[64][65];
  int g = blockIdx.z;
  int k0 = blockIdx.x * 64, n0 = blockIdx.y * 64;
  const float* Wg = W + (size_t)g * K * N;
  u16* Og = Wt + (size_t)g * N * K;
  int tid = threadIdx.x;
  int rr = tid >> 4, cc = (tid & 15) * 4;
#pragma unroll
  for (int r = 0; r < 4; ++r) {
    int k = rr + r * 16;
    float4 v = *(const float4*)(Wg + (size_t)(k0 + k) * N + n0 + cc);
    tile[k][cc] = v.x; tile[k][cc + 1] = v.y; tile[k][cc + 2] = v.z; tile[k][cc + 3] = v.w;
  }
  __syncthreads();
  int nr = tid >> 3, kc = (tid & 7) * 8;
#pragma unroll
  for (int p = 0; p < 2; ++p) {
    int n = nr + p * 32;
    u16 tmp[8];
#pragma unroll
    for (int j = 0; j < 8; ++j) tmp[j] = f2bf(tile[kc + j][n]);
    *(uint4*)(Og + (size_t)(n0 + n) * K + k0 + kc) = *(uint4*)tmp;
  }
}

// ---------------- f32 -> bf16 cast (4 elems/thread)
__global__ __launch_bounds__(256) void cast_bf16k(const float* __restrict__ X, u16* __restrict__ Y) {
  size_t i = ((size_t)blockIdx.x * 256 + threadIdx.x) * 4;
  float4 v = *(const float4*)(X + i);
  u16 t[4] = { f2bf(v.x), f2bf(v.y), f2bf(v.z), f2bf(v.w) };
  *(uint2*)(Y + i) = *(uint2*)t;
}

// ---------------- batched bf16 GEMM, templated N-tile (128 or 64)
// A row-select: (a_g0 + z)/a_div picks A matrix (stride a_stride elems)
// Wt: [z][N][K] bf16; C: C + z*c_stride
#define BM 128
#define BK 32
#define LDK 32   // unpadded: required by global_load_lds lane mapping

template<int BN_>
__global__ __launch_bounds__(256) void gemm_t(
    const u16* __restrict__ A, long a_stride, int a_div, int a_g0,
    const u16* __restrict__ Wt, const float* __restrict__ bias,
    u16* __restrict__ C, long c_stride, int N, int K, int relu_flag) {
  constexpr int JT = BN_ / 32;       // B sub-tiles per wave (4 or 2)
  constexpr int BROWS = BN_ / 4;     // B rows staged per wave (32 or 16)
  int gz = blockIdx.z;
  const u16* Ag = A + (size_t)((a_g0 + gz) / a_div) * a_stride;
  const u16* Wg = Wt + (size_t)gz * N * K;
  u16* Cg = C + (size_t)gz * c_stride;
  int m0 = blockIdx.x * BM, n0 = blockIdx.y * BN_;

  __shared__ __align__(16) u16 As[BM * LDK];
  __shared__ __align__(16) u16 Bs[BN_ * LDK];

  int tid = threadIdx.x;
  int wv = tid >> 6, ln = tid & 63;
  int wm = (wv >> 1) * 64, wn = (wv & 1) * (BN_ / 2);
  int lr = ln & 15, lk = (ln >> 4) * 8;

  // staging map: A wave wv -> rows [32wv,32wv+32), B wave wv -> rows [BROWS*wv, ...)
  int sr = ln >> 2;           // 0..15
  int sc = (ln & 3) * 8;      // u16 col 0,8,16,24
  const u16* aG = Ag + (size_t)(m0 + wv * 32 + sr) * K + sc;
  const u16* bG = Wg + (size_t)(n0 + wv * BROWS + sr) * K + sc;
  u16* aL0 = As + (wv * 32) * LDK;
  u16* aL1 = aL0 + 16 * LDK;
  u16* bL0 = Bs + (wv * BROWS) * LDK;

  f32x4 acc[4][JT];
#pragma unroll
  for (int i = 0; i < 4; ++i)
#pragma unroll
    for (int j = 0; j < JT; ++j)
      acc[i][j] = (f32x4){0.f, 0.f, 0.f, 0.f};

  int nk = K / BK;
  for (int ks = 0; ks < nk; ++ks) {
    __syncthreads();                       // prev ds_reads done before overwrite
    gll(aG + ks * BK, aL0);
    gll(aG + ks * BK + (size_t)16 * K, aL1);
    gll(bG + ks * BK, bL0);
    if (BN_ == 128) gll(bG + ks * BK + (size_t)16 * K, bL0 + 16 * LDK);
    __syncthreads();                       // drains vmcnt before barrier
    bf16x8 af[4], bfr[JT];
#pragma unroll
    for (int i = 0; i < 4; ++i) {
      union { uint4 u; bf16x8 v; } ua;
      ua.u = *(const uint4*)(As + (wm + i * 16 + lr) * LDK + lk);
      af[i] = ua.v;
    }
#pragma unroll
    for (int j = 0; j < JT; ++j) {
      union { uint4 u; bf16x8 v; } ub;
      ub.u = *(const uint4*)(Bs + (wn + j * 16 + lr) * LDK + lk);
      bfr[j] = ub.v;
    }
#pragma unroll
    for (int i = 0; i < 4; ++i)
#pragma unroll
      for (int j = 0; j < JT; ++j)
        acc[i][j] = __builtin_amdgcn_mfma_f32_16x16x32_bf16(af[i], bfr[j], acc[i][j], 0, 0, 0);
  }

  // epilogue: D row = (lane>>4)*4+reg, col = lane&15
  int mr = (ln >> 4) * 4;
#pragma unroll
  for (int i = 0; i < 4; ++i) {
#pragma unroll
    for (int j = 0; j < JT; ++j) {
      int n = n0 + wn + j * 16 + lr;
      float bv = bias[(size_t)gz * N + n];
#pragma unroll
      for (int r = 0; r < 4; ++r) {
        int m = m0 + wm + i * 16 + mr + r;
        float v = acc[i][j][r] + bv;
        if (relu_flag) v = fmaxf(v, 0.f);
        Cg[(size_t)m * N + n] = f2bf(v);
      }
    }
  }
}

// ---------------- rowwise LayerNorm * gain + beta, ReLU, in-place on bf16
// launch with blockDim = N/8 (128 or 256); gain/beta pre-offset; grp = row/B_
__global__ __launch_bounds__(256) void ln_affine_relu(
    u16* __restrict__ H, const float* __restrict__ gain, const float* __restrict__ beta, int N) {
  __shared__ float red[4];
  size_t row = blockIdx.x;
  int grp = (int)(row / B_);
  u16* hp = H + row * N;
  const float* gp = gain + (size_t)grp * N;
  const float* bp = beta + (size_t)grp * N;
  int tid = threadIdx.x;
  int nw = blockDim.x >> 6;
  union { uint4 u; u16 s[8]; } pk;
  pk.u = *(const uint4*)(hp + tid * 8);
  float v[8], s = 0.f;
#pragma unroll
  for (int j = 0; j < 8; ++j) { v[j] = bf2f(pk.s[j]); s += v[j]; }
  for (int off = 32; off > 0; off >>= 1) s += __shfl_down(s, off, 64);
  if ((tid & 63) == 0) red[tid >> 6] = s;
  __syncthreads();
  float tot = 0.f;
  for (int i = 0; i < nw; ++i) tot += red[i];
  float mu = tot / (float)N;
  float q = 0.f;
#pragma unroll
  for (int j = 0; j < 8; ++j) { float d = v[j] - mu; q += d * d; }
  __syncthreads();
  for (int off = 32; off > 0; off >>= 1) q += __shfl_down(q, off, 64);
  if ((tid & 63) == 0) red[tid >> 6] = q;
  __syncthreads();
  tot = 0.f;
  for (int i = 0; i < nw; ++i) tot += red[i];
  float rstd = rsqrtf(tot / (float)N + 1e-5f);
  float4 ga = *(const float4*)(gp + tid * 8);
  float4 gb2 = *(const float4*)(gp + tid * 8 + 4);
  float4 ba = *(const float4*)(bp + tid * 8);
  float4 bb2 = *(const float4*)(bp + tid * 8 + 4);
  float gg[8] = { ga.x, ga.y, ga.z, ga.w, gb2.x, gb2.y, gb2.z, gb2.w };
  float bt[8] = { ba.x, ba.y, ba.z, ba.w, bb2.x, bb2.y, bb2.z, bb2.w };
  u16 o[8];
#pragma unroll
  for (int j = 0; j < 8; ++j) {
    float y = (v[j] - mu) * rstd * gg[j] + bt[j];
    o[j] = f2bf(fmaxf(y, 0.f));
  }
  *(uint4*)(hp + tid * 8) = *(uint4*)o;
}

// ---------------- pack gate weights: W[t][k][e] -> out4[k4][j][0..3], j=t*L+e
__global__ __launch_bounds__(256) void prep_gw4(
    const float* __restrict__ W, float* __restrict__ out4,
    int G, int K, int E, int L) {
  int id = blockIdx.x * 256 + threadIdx.x;
  int tot = (K >> 2) * 32;
  if (id >= tot) return;
  int k4 = id >> 5, j = id & 31;
  int t = j / L, e = j % L;
  float4 v = { 0.f, 0.f, 0.f, 0.f };
  if (t < G && e < E) {
    const float* w = W + (size_t)t * K * E + e;
    v.x = w[(size_t)(k4 * 4 + 0) * E];
    v.y = w[(size_t)(k4 * 4 + 1) * E];
    v.z = w[(size_t)(k4 * 4 + 2) * E];
    v.w = w[(size_t)(k4 * 4 + 3) * E];
  }
  *(float4*)(out4 + (size_t)id * 4) = v;
}

// ---------------- fast gates: 8 rows/block, lane j=t*L+e; unroll-4, 4 accumulators
__global__ __launch_bounds__(256) void gates_fast(
    const void* __restrict__ X, int is_bf16, long t_stride,
    const float* __restrict__ GW4, const float* __restrict__ GB,
    float* __restrict__ out, int G, int K, int E, int L) {
  int tid = threadIdx.x;
  int rl = tid >> 5;             // row within block, 0..7
  int j  = tid & 31;
  int t = j / L, e = j % L;
  int b = blockIdx.x * 8 + rl;
  int tr = (t < G) ? t : (G - 1);   // clamp for safe loads on dead lanes
  int K4 = K >> 2;
  float ac0 = 0.f, ac1 = 0.f, ac2 = 0.f, ac3 = 0.f;
  if (is_bf16) {
    const u16* xr = (const u16*)X + (size_t)tr * t_stride + (size_t)b * K;
    for (int k4 = 0; k4 < K4; k4 += 4) {
      uint2 p0 = *(const uint2*)(xr + (k4 + 0) * 4);
      uint2 p1 = *(const uint2*)(xr + (k4 + 1) * 4);
      uint2 p2 = *(const uint2*)(xr + (k4 + 2) * 4);
      uint2 p3 = *(const uint2*)(xr + (k4 + 3) * 4);
      float4 q0 = *(const float4*)(GW4 + ((size_t)(k4 + 0) * 32 + j) * 4);
      float4 q1 = *(const float4*)(GW4 + ((size_t)(k4 + 1) * 32 + j) * 4);
      float4 q2 = *(const float4*)(GW4 + ((size_t)(k4 + 2) * 32 + j) * 4);
      float4 q3 = *(const float4*)(GW4 + ((size_t)(k4 + 3) * 32 + j) * 4);
      ac0 += bf2f((u16)(p0.x & 0xffffu)) * q0.x + bf2f((u16)(p0.x >> 16)) * q0.y
           + bf2f((u16)(p0.y & 0xffffu)) * q0.z + bf2f((u16)(p0.y >> 16)) * q0.w;
      ac1 += bf2f((u16)(p1.x & 0xffffu)) * q1.x + bf2f((u16)(p1.x >> 16)) * q1.y
           + bf2f((u16)(p1.y & 0xffffu)) * q1.z + bf2f((u16)(p1.y >> 16)) * q1.w;
      ac2 += bf2f((u16)(p2.x & 0xffffu)) * q2.x + bf2f((u16)(p2.x >> 16)) * q2.y
           + bf2f((u16)(p2.y & 0xffffu)) * q2.z + bf2f((u16)(p2.y >> 16)) * q2.w;
      ac3 += bf2f((u16)(p3.x & 0xffffu)) * q3.x + bf2f((u16)(p3.x >> 16)) * q3.y
           + bf2f((u16)(p3.y & 0xffffu)) * q3.z + bf2f((u16)(p3.y >> 16)) * q3.w;
    }
  } else {
    const float* xr = (const float*)X + (size_t)tr * t_stride + (size_t)b * K;
    for (int k4 = 0; k4 < K4; k4 += 4) {
      float4 x0 = *(const float4*)(xr + (k4 + 0) * 4);
      float4 x1 = *(const float4*)(xr + (k4 + 1) * 4);
      float4 x2 = *(const float4*)(xr + (k4 + 2) * 4);
      float4 x3 = *(const float4*)(xr + (k4 + 3) * 4);
      float4 q0 = *(const float4*)(GW4 + ((size_t)(k4 + 0) * 32 + j) * 4);
      float4 q1 = *(const float4*)(GW4 + ((size_t)(k4 + 1) * 32 + j) * 4);
      float4 q2 = *(const float4*)(GW4 + ((size_t)(k4 + 2) * 32 + j) * 4);
      float4 q3 = *(const float4*)(GW4 + ((size_t)(k4 + 3) * 32 + j) * 4);
      ac0 += x0.x * q0.x + x0.y * q0.y + x0.z * q0.z + x0.w * q0.w;
      ac1 += x1.x * q1.x + x1.y * q1.y + x1.z * q1.z + x1.w * q1.w;
      ac2 += x2.x * q2.x + x2.y * q2.y + x2.z * q2.z + x2.w * q2.w;
      ac3 += x3.x * q3.x + x3.y * q3.y + x3.z * q3.z + x3.w * q3.w;
    }
  }
  float acc = (ac0 + ac1) + (ac2 + ac3);
  bool valid = (t < G) && (e < E);
  float lg = valid ? (acc + GB[t * E + e]) : -1e30f;
  float m = lg;
  for (int o = L >> 1; o > 0; o >>= 1) m = fmaxf(m, __shfl_xor(m, o, L));
  float ex = valid ? expf(lg - m) : 0.f;
  float sm = ex;
  for (int o = L >> 1; o > 0; o >>= 1) sm += __shfl_xor(sm, o, L);
  if (valid) out[((size_t)t * B_ + b) * E + e] = ex / sm;
}

// ---------------- MMoE mixing: task_hs[t]=sum_e g[t,e]*eo[e]; shared=mean_t
__global__ __launch_bounds__(256) void mmoe_mix(
    const u16* __restrict__ eo, const float* __restrict__ gates,
    u16* __restrict__ task_hs, u16* __restrict__ shared_h) {
  __shared__ float g[24];
  int b = blockIdx.x, tid = threadIdx.x;
  if (tid < 24) g[tid] = gates[((size_t)(tid >> 3) * B_ + b) * 8 + (tid & 7)];
  __syncthreads();
  int o = tid * 2;
  float a0[3] = {0, 0, 0}, a1[3] = {0, 0, 0};
#pragma unroll
  for (int e = 0; e < 8; ++e) {
    u32 w = *(const u32*)(eo + ((size_t)e * B_ + b) * 512 + o);
    float v0 = bf2f((u16)(w & 0xffffu)), v1 = bf2f((u16)(w >> 16));
#pragma unroll
    for (int t = 0; t < 3; ++t) { a0[t] += g[t * 8 + e] * v0; a1[t] += g[t * 8 + e] * v1; }
  }
  float s0 = 0.f, s1 = 0.f;
#pragma unroll
  for (int t = 0; t < 3; ++t) {
    u16 p[2] = { f2bf(a0[t]), f2bf(a1[t]) };
    *(u32*)(task_hs + ((size_t)t * B_ + b) * 512 + o) = *(u32*)p;
    s0 += a0[t]; s1 += a1[t];
  }
  u16 p[2] = { f2bf(s0 * (1.f / 3.f)), f2bf(s1 * (1.f / 3.f)) };
  *(u32*)(shared_h + (size_t)b * 512 + o) = *(u32*)p;
}

// ---------------- CGC mixing (task experts first, then shared; opt shared-gate out)
__global__ __launch_bounds__(256) void cgc_mix(
    const u16* __restrict__ to, const u16* __restrict__ so,
    const float* __restrict__ g, const float* __restrict__ sg,
    u16* __restrict__ task_out, u16* __restrict__ shared_out) {
  int b = blockIdx.x, o = threadIdx.x;
  float tv[9], sv[4];
#pragma unroll
  for (int j = 0; j < 9; ++j) tv[j] = bf2f(to[((size_t)j * B_ + b) * 256 + o]);
#pragma unroll
  for (int s = 0; s < 4; ++s) sv[s] = bf2f(so[((size_t)s * B_ + b) * 256 + o]);
#pragma unroll
  for (int t = 0; t < 3; ++t) {
    const float* gt = g + ((size_t)t * B_ + b) * 7;
    float a = gt[0] * tv[t * 3] + gt[1] * tv[t * 3 + 1] + gt[2] * tv[t * 3 + 2];
#pragma unroll
    for (int s = 0; s < 4; ++s) a += gt[3 + s] * sv[s];
    task_out[((size_t)t * B_ + b) * 256 + o] = f2bf(a);
  }
  if (shared_out) {
    const float* sp = sg + (size_t)b * 13;
    float a = 0.f;
#pragma unroll
    for (int j = 0; j < 9; ++j) a += sp[j] * tv[j];
#pragma unroll
    for (int s = 0; s < 4; ++s) a += sp[9 + s] * sv[s];
    shared_out[(size_t)b * 256 + o] = f2bf(a);
  }
}

// ---------------- tower head: out[t*B+b] = th[t,b,:] . w2[t,:] + b2[t]  (fp32 out)
__global__ __launch_bounds__(256) void tower_out(
    const u16* __restrict__ th, const float* __restrict__ w2,
    const float* __restrict__ b2, float* __restrict__ out) {
  int r = blockIdx.x * 4 + (threadIdx.x >> 6);
  int lane = threadIdx.x & 63;
  int t = r / B_;
  const u16* row = th + (size_t)r * 256;
  u16 hv[4];
  *(uint2*)hv = *(const uint2*)(row + lane * 4);
  float4 wv = *(const float4*)(w2 + t * 256 + lane * 4);
  float s = bf2f(hv[0]) * wv.x + bf2f(hv[1]) * wv.y + bf2f(hv[2]) * wv.z + bf2f(hv[3]) * wv.w;
  for (int off = 32; off > 0; off >>= 1) s += __shfl_down(s, off, 64);
  if (lane == 0) out[r] = s + b2[t];
}

extern "C" void kernel_launch(void* const* d_in, const int* in_sizes, int n_in,
                              void* d_out, int out_size, void* d_ws, size_t ws_size,
                              hipStream_t stream) {
  (void)in_sizes; (void)n_in; (void)out_size;
  const float* x      = (const float*)d_in[0];
  const float* m_w1   = (const float*)d_in[1];
  const float* m_b1   = (const float*)d_in[2];
  const float* m_g    = (const float*)d_in[3];
  const float* m_be   = (const float*)d_in[4];
  const float* m_w2   = (const float*)d_in[5];
  const float* m_b2   = (const float*)d_in[6];
  const float* m_gw   = (const float*)d_in[7];
  const float* m_gb   = (const float*)d_in[8];
  const float* c0_sw1 = (const float*)d_in[9];
  const float* c0_sb1 = (const float*)d_in[10];
  const float* c0_sg  = (const float*)d_in[11];
  const float* c0_sbe = (const float*)d_in[12];
  const float* c0_sw2 = (const float*)d_in[13];
  const float* c0_sb2 = (const float*)d_in[14];
  const float* c0_tw1 = (const float*)d_in[15];
  const float* c0_tb1 = (const float*)d_in[16];
  const float* c0_tg  = (const float*)d_in[17];
  const float* c0_tbe = (const float*)d_in[18];
  const float* c0_tw2 = (const float*)d_in[19];
  const float* c0_tb2 = (const float*)d_in[20];
  const float* c0_gw  = (const float*)d_in[21];
  const float* c0_gb  = (const float*)d_in[22];
  const float* c0_sgw = (const float*)d_in[23];
  const float* c0_sgb = (const float*)d_in[24];
  const float* c1_sw1 = (const float*)d_in[25];
  const float* c1_sb1 = (const float*)d_in[26];
  const float* c1_sg  = (const float*)d_in[27];
  const float* c1_sbe = (const float*)d_in[28];
  const float* c1_sw2 = (const float*)d_in[29];
  const float* c1_sb2 = (const float*)d_in[30];
  const float* c1_tw1 = (const float*)d_in[31];
  const float* c1_tb1 = (const float*)d_in[32];
  const float* c1_tg  = (const float*)d_in[33];
  const float* c1_tbe = (const float*)d_in[34];
  const float* c1_tw2 = (const float*)d_in[35];
  const float* c1_tb2 = (const float*)d_in[36];
  const float* c1_gw  = (const float*)d_in[37];
  const float* c1_gb  = (const float*)d_in[38];
  const float* tw1    = (const float*)d_in[39];
  const float* tb1    = (const float*)d_in[40];
  const float* tw2    = (const float*)d_in[41];
  const float* tb2    = (const float*)d_in[42];

  // ---- static region layout (171 MB total, phase-aliased) ----
  const size_t MB = 1024 * 1024;
  char* ws = (char*)d_ws;
  size_t off = 0;
  u16* arena = (u16*)(ws + off); off += 24 * MB;   // transposed-weight arena (per phase)
  u16* eoR   = (u16*)(ws + off); off += 64 * MB;   // MMoE eo[8,B,512] | CGC so+to
  u16* hbuf  = (u16*)(ws + off); off += 32 * MB;   // gw4 packs (pre-GEMM) | expert hidden | tower th
  u16* thsR  = (u16*)(ws + off); off += 24 * MB;   // MMoE wT e4-7 | task_hs | task2
  u16* xbR   = (u16*)(ws + off); off += 16 * MB;   // xb | task1+shared1
  u16* shR   = (u16*)(ws + off); off += 8 * MB;    // shared_h
  float* gmo = (float*)(ws + off); off += 3 * MB;  // gates out: gmo|g0|sg0|g1
  if (ws_size < off) return;

  float* g0  = gmo + (size_t)3 * B_ * 8;
  float* sg0 = g0  + (size_t)3 * B_ * 7;
  float* g1  = sg0 + (size_t)B_ * 13;

  u16* xb       = xbR;
  u16* eo       = eoR;
  u16* task_hs  = thsR;
  u16* shared_h = shR;
  u16* soD      = eoR;                             // [4,B,256]
  u16* toD      = eoR + (size_t)4 * B_ * 256;      // [9,B,256]
  u16* task1    = xbR;                             // [3,B,256]
  u16* shared1  = xbR + (size_t)3 * B_ * 256;      // [B,256]
  u16* task2    = thsR;                            // [3,B,256]
  u16* thbuf    = hbuf;                            // [3,B,256]

  // gate-weight packs live at the front of hbuf (used strictly before GEMMs write it)
  float* gw4a = (float*)hbuf;          // up to 128 KB
  float* gw4b = (float*)hbuf + 32768;  // second 128 KB slot

  dim3 blk(256);
  cast_bf16k<<<8192, blk, 0, stream>>>(x, xb);

  // ---- MMoE gate (fp32, coalesced) ----
  prep_gw4<<<32, blk, 0, stream>>>(m_gw, gw4a, 3, 1024, 8, 8);
  gates_fast<<<B_ / 8, blk, 0, stream>>>(x, 0, 0L, gw4a, m_gb, gmo, 3, 1024, 8, 8);

  // ---- MMoE weights: all 8 experts transposed upfront (arena: e0-3, thsR: e4-7) ----
  {
    u16* w1t_lo = arena;                                // 4 x [2048][1024] = 16 MB
    u16* w2t_lo = arena + (size_t)4 * 2048 * 1024;      // 4 x [512][2048]  =  8 MB
    u16* w1t_hi = thsR;
    u16* w2t_hi = thsR + (size_t)4 * 2048 * 1024;
    transpose_cast<<<dim3(16, 32, 4), blk, 0, stream>>>(m_w1, w1t_lo, 1024, 2048);
    transpose_cast<<<dim3(32,  8, 4), blk, 0, stream>>>(m_w2, w2t_lo, 2048, 512);
    transpose_cast<<<dim3(16, 32, 4), blk, 0, stream>>>(m_w1 + (size_t)4 * 1024 * 2048, w1t_hi, 1024, 2048);
    transpose_cast<<<dim3(32,  8, 4), blk, 0, stream>>>(m_w2 + (size_t)4 * 2048 * 512,  w2t_hi, 2048, 512);
    for (int e = 0; e < 8; ++e) {
      u16* w1t = (e < 4 ? w1t_lo : w1t_hi) + (size_t)(e & 3) * 2048 * 1024;
      u16* w2t = (e < 4 ? w2t_lo : w2t_hi) + (size_t)(e & 3) * 512 * 2048;
      gemm_t<128><<<dim3(64, 16, 1), blk, 0, stream>>>(
          xb, 0L, 1, 0, w1t, m_b1 + (size_t)e * 2048, hbuf, 0L, 2048, 1024, 0);
      ln_affine_relu<<<B_, 256, 0, stream>>>(hbuf, m_g + (size_t)e * 2048, m_be + (size_t)e * 2048, 2048);
      gemm_t<64><<<dim3(64, 8, 1), blk, 0, stream>>>(
          hbuf, 0L, 1, 0, w2t, m_b2 + (size_t)e * 512,
          eo + (size_t)e * B_ * 512, 0L, 512, 2048, 0);
    }
  }
  mmoe_mix<<<B_, blk, 0, stream>>>(eo, gmo, task_hs, shared_h);  // overwrites thsR — MMoE GEMMs done

  // ---- CGC0 gates (hbuf free again until CGC0 GEMMs) ----
  prep_gw4<<<16, blk, 0, stream>>>(c0_gw, gw4a, 3, 512, 7, 8);
  prep_gw4<<<16, blk, 0, stream>>>(c0_sgw, gw4b, 1, 512, 13, 16);
  gates_fast<<<B_ / 8, blk, 0, stream>>>(task_hs, 1, (long)B_ * 512, gw4a, c0_gb, g0, 3, 512, 7, 8);
  gates_fast<<<B_ / 8, blk, 0, stream>>>(shared_h, 1, 0L, gw4b, c0_sgb, sg0, 1, 512, 13, 16);

  // ---- CGC layer 0 (arena: sw1t 4MB | sw2t 2MB | tw1t 9MB | tw2t 4.5MB) ----
  {
    u16* sw1t = arena;
    u16* sw2t = sw1t + (size_t)4 * 1024 * 512;
    u16* tw1t = sw2t + (size_t)4 * 256 * 1024;
    u16* tw2t = tw1t + (size_t)9 * 1024 * 512;
    transpose_cast<<<dim3( 8, 16, 4), blk, 0, stream>>>(c0_sw1, sw1t, 512, 1024);
    transpose_cast<<<dim3(16,  4, 4), blk, 0, stream>>>(c0_sw2, sw2t, 1024, 256);
    transpose_cast<<<dim3( 8, 16, 9), blk, 0, stream>>>(c0_tw1, tw1t, 512, 1024);
    transpose_cast<<<dim3(16,  4, 9), blk, 0, stream>>>(c0_tw2, tw2t, 1024, 256);
    for (int g0i = 0; g0i < 4; g0i += 2) {
      gemm_t<128><<<dim3(64, 8, 2), blk, 0, stream>>>(
          shared_h, 0L, 1, 0, sw1t + (size_t)g0i * 1024 * 512, c0_sb1 + (size_t)g0i * 1024,
          hbuf, (long)B_ * 1024, 1024, 512, 0);
      ln_affine_relu<<<2 * B_, 128, 0, stream>>>(hbuf, c0_sg + (size_t)g0i * 1024, c0_sbe + (size_t)g0i * 1024, 1024);
      gemm_t<64><<<dim3(64, 4, 2), blk, 0, stream>>>(
          hbuf, (long)B_ * 1024, 1, 0, sw2t + (size_t)g0i * 256 * 1024, c0_sb2 + (size_t)g0i * 256,
          soD + (size_t)g0i * B_ * 256, (long)B_ * 256, 256, 1024, 0);
    }
    for (int g0i = 0; g0i < 9; g0i += 2) {
      int gsz = (g0i + 2 <= 9) ? 2 : 1;
      gemm_t<128><<<dim3(64, 8, gsz), blk, 0, stream>>>(
          task_hs, (long)B_ * 512, 3, g0i, tw1t + (size_t)g0i * 1024 * 512, c0_tb1 + (size_t)g0i * 1024,
          hbuf, (long)B_ * 1024, 1024, 512, 0);
      ln_affine_relu<<<gsz * B_, 128, 0, stream>>>(hbuf, c0_tg + (size_t)g0i * 1024, c0_tbe + (size_t)g0i * 1024, 1024);
      gemm_t<64><<<dim3(64, 4, gsz), blk, 0, stream>>>(
          hbuf, (long)B_ * 1024, 1, 0, tw2t + (size_t)g0i * 256 * 1024, c0_tb2 + (size_t)g0i * 256,
          toD + (size_t)g0i * B_ * 256, (long)B_ * 256, 256, 1024, 0);
    }
  }
  cgc_mix<<<B_, blk, 0, stream>>>(toD, soD, g0, sg0, task1, shared1);

  // ---- CGC1 gate ----
  prep_gw4<<<8, blk, 0, stream>>>(c1_gw, gw4a, 3, 256, 7, 8);
  gates_fast<<<B_ / 8, blk, 0, stream>>>(task1, 1, (long)B_ * 256, gw4a, c1_gb, g1, 3, 256, 7, 8);

  // ---- CGC layer 1 (arena: sw1t 2MB | sw2t 2MB | tw1t 4.5MB | tw2t 4.5MB) ----
  {
    u16* sw1t = arena;
    u16* sw2t = sw1t + (size_t)4 * 1024 * 256;
    u16* tw1t = sw2t + (size_t)4 * 256 * 1024;
    u16* tw2t = tw1t + (size_t)9 * 1024 * 256;
    transpose_cast<<<dim3( 4, 16, 4), blk, 0, stream>>>(c1_sw1, sw1t, 256, 1024);
    transpose_cast<<<dim3(16,  4, 4), blk, 0, stream>>>(c1_sw2, sw2t, 1024, 256);
    transpose_cast<<<dim3( 4, 16, 9), blk, 0, stream>>>(c1_tw1, tw1t, 256, 1024);
    transpose_cast<<<dim3(16,  4, 9), blk, 0, stream>>>(c1_tw2, tw2t, 1024, 256);
    for (int g0i = 0; g0i < 4; g0i += 2) {
      gemm_t<128><<<dim3(64, 8, 2), blk, 0, stream>>>(
          shared1, 0L, 1, 0, sw1t + (size_t)g0i * 1024 * 256, c1_sb1 + (size_t)g0i * 1024,
          hbuf, (long)B_ * 1024, 1024, 256, 0);
      ln_affine_relu<<<2 * B_, 128, 0, stream>>>(hbuf, c1_sg + (size_t)g0i * 1024, c1_sbe + (size_t)g0i * 1024, 1024);
      gemm_t<64><<<dim3(64, 4, 2), blk, 0, stream>>>(
          hbuf, (long)B_ * 1024, 1, 0, sw2t + (size_t)g0i * 256 * 1024, c1_sb2 + (size_t)g0i * 256,
          soD + (size_t)g0i * B_ * 256, (long)B_ * 256, 256, 1024, 0);
    }
    for (int g0i = 0; g0i < 9; g0i += 2) {
      int gsz = (g0i + 2 <= 9) ? 2 : 1;
      gemm_t<128><<<dim3(64, 8, gsz), blk, 0, stream>>>(
          task1, (long)B_ * 256, 3, g0i, tw1t + (size_t)g0i * 1024 * 256, c1_tb1 + (size_t)g0i * 1024,
          hbuf, (long)B_ * 1024, 1024, 256, 0);
      ln_affine_relu<<<gsz * B_, 128, 0, stream>>>(hbuf, c1_tg + (size_t)g0i * 1024, c1_tbe + (size_t)g0i * 1024, 1024);
      gemm_t<64><<<dim3(64, 4, gsz), blk, 0, stream>>>(
          hbuf, (long)B_ * 1024, 1, 0, tw2t + (size_t)g0i * 256 * 1024, c1_tb2 + (size_t)g0i * 256,
          toD + (size_t)g0i * B_ * 256, (long)B_ * 256, 256, 1024, 0);
    }
  }
  cgc_mix<<<B_, blk, 0, stream>>>(toD, soD, g1, nullptr, task2, nullptr);

  // ---- towers ----
  {
    u16* twt = arena;
    transpose_cast<<<dim3(4, 4, 3), blk, 0, stream>>>(tw1, twt, 256, 256);
    gemm_t<64><<<dim3(64, 4, 3), blk, 0, stream>>>(
        task2, (long)B_ * 256, 1, 0, twt, tb1, thbuf, (long)B_ * 256, 256, 256, 1);
    tower_out<<<6144, blk, 0, stream>>>(thbuf, tw2, tb2, (float*)d_out);
  }
}